// Round 1
// baseline (669.865 us; speedup 1.0000x reference)
//
#include <hip/hip_runtime.h>

#define M_TOK 8192
#define N_OUT 4096
#define K_IN  4096

typedef _Float16 f16x8 __attribute__((ext_vector_type(8)));
typedef _Float16 f16x4 __attribute__((ext_vector_type(4)));
typedef float    f32x4 __attribute__((ext_vector_type(4)));

// ---------------- mean(|W|) reduction ----------------

__global__ void k_absmean_partial(const float* __restrict__ w, double* __restrict__ partials) {
    const int n4 = (N_OUT * K_IN) / 4;
    double s = 0.0;
    for (int i = blockIdx.x * blockDim.x + threadIdx.x; i < n4; i += gridDim.x * blockDim.x) {
        float4 v = reinterpret_cast<const float4*>(w)[i];
        s += (double)fabsf(v.x);
        s += (double)fabsf(v.y);
        s += (double)fabsf(v.z);
        s += (double)fabsf(v.w);
    }
    #pragma unroll
    for (int off = 32; off > 0; off >>= 1) s += __shfl_down(s, off, 64);
    __shared__ double sm[4];
    if ((threadIdx.x & 63) == 0) sm[threadIdx.x >> 6] = s;
    __syncthreads();
    if (threadIdx.x == 0) partials[blockIdx.x] = sm[0] + sm[1] + sm[2] + sm[3];
}

__global__ void k_absmean_final(const double* __restrict__ partials, float* __restrict__ meanp) {
    double s = 0.0;
    for (int i = threadIdx.x; i < 1024; i += 256) s += partials[i];
    #pragma unroll
    for (int off = 32; off > 0; off >>= 1) s += __shfl_down(s, off, 64);
    __shared__ double sm[4];
    if ((threadIdx.x & 63) == 0) sm[threadIdx.x >> 6] = s;
    __syncthreads();
    if (threadIdx.x == 0)
        *meanp = (float)((sm[0] + sm[1] + sm[2] + sm[3]) / (double)((long long)N_OUT * K_IN));
}

// ---------------- ternarize W -> fp16, cast x -> fp16 ----------------

__global__ void k_ternarize(const float* __restrict__ w, const float* __restrict__ meanp,
                            _Float16* __restrict__ wt) {
    const float t = *meanp;
    const int n4 = (N_OUT * K_IN) / 4;
    for (int i = blockIdx.x * blockDim.x + threadIdx.x; i < n4; i += gridDim.x * blockDim.x) {
        float4 v = reinterpret_cast<const float4*>(w)[i];
        f16x4 r;
        r[0] = (_Float16)((fabsf(v.x) > t) ? ((v.x > 0.f) ? 1.f : -1.f) : 0.f);
        r[1] = (_Float16)((fabsf(v.y) > t) ? ((v.y > 0.f) ? 1.f : -1.f) : 0.f);
        r[2] = (_Float16)((fabsf(v.z) > t) ? ((v.z > 0.f) ? 1.f : -1.f) : 0.f);
        r[3] = (_Float16)((fabsf(v.w) > t) ? ((v.w > 0.f) ? 1.f : -1.f) : 0.f);
        reinterpret_cast<f16x4*>(wt)[i] = r;
    }
}

__global__ void k_cvt_x(const float* __restrict__ x, _Float16* __restrict__ xh) {
    const int n4 = (M_TOK * K_IN) / 4;
    for (int i = blockIdx.x * blockDim.x + threadIdx.x; i < n4; i += gridDim.x * blockDim.x) {
        float4 v = reinterpret_cast<const float4*>(x)[i];
        f16x4 r;
        r[0] = (_Float16)v.x;
        r[1] = (_Float16)v.y;
        r[2] = (_Float16)v.z;
        r[3] = (_Float16)v.w;
        reinterpret_cast<f16x4*>(xh)[i] = r;
    }
}

// ---------------- fp16 MFMA GEMM: C[m][n] = sum_k A[m][k] * B[n][k] ----------------
// m97 structure: 128x128 tile, BK=32, 4 waves (2x2), each wave 64x64 = 4x4 frags of 16x16x32.

__device__ __forceinline__ void g2lds16(const _Float16* g, _Float16* l) {
    __builtin_amdgcn_global_load_lds(
        (const __attribute__((address_space(1))) unsigned int*)(g),
        (__attribute__((address_space(3))) unsigned int*)(l), 16, 0, 0);
}

__global__ __launch_bounds__(256) void k_gemm(const _Float16* __restrict__ A,
                                              const _Float16* __restrict__ B,
                                              float* __restrict__ C) {
    __shared__ _Float16 sA[128 * 32];
    __shared__ _Float16 sB[128 * 32];
    const int t   = threadIdx.x;
    const int l   = t & 63;
    const int wv  = t >> 6;
    const int wr  = (wv >> 1) << 6;    // wave row offset (0 or 64)
    const int wc  = (wv & 1) << 6;     // wave col offset (0 or 64)
    const int lr  = l & 15;            // fragment row/col index
    const int lko = (l >> 4) << 3;     // k offset within BK: 0,8,16,24

    const int bm = blockIdx.y, bn = blockIdx.x;

    f32x4 acc[4][4];
    const f32x4 vzero = {0.f, 0.f, 0.f, 0.f};
    #pragma unroll
    for (int i = 0; i < 4; ++i)
        #pragma unroll
        for (int j = 0; j < 4; ++j) acc[i][j] = vzero;

    // staging: thread t loads 16B = 8 halfs; row t>>2 (and +64), chunk (t&3)*8 halfs
    const _Float16* gA = A + ((size_t)(bm * 128 + (t >> 2)) * K_IN) + (t & 3) * 8;
    const _Float16* gB = B + ((size_t)(bn * 128 + (t >> 2)) * K_IN) + (t & 3) * 8;
    _Float16* lA = sA + wv * 512;      // wave-uniform LDS base; HW adds lane*16B
    _Float16* lB = sB + wv * 512;

    for (int k0 = 0; k0 < K_IN; k0 += 32) {
        g2lds16(gA + k0,                     lA);
        g2lds16(gA + k0 + (size_t)64 * K_IN, lA + 2048);
        g2lds16(gB + k0,                     lB);
        g2lds16(gB + k0 + (size_t)64 * K_IN, lB + 2048);
        __syncthreads();   // compiler drains vmcnt(0) before s_barrier

        f16x8 af[4], bf[4];
        #pragma unroll
        for (int m = 0; m < 4; ++m)
            af[m] = *reinterpret_cast<const f16x8*>(&sA[(wr + m * 16 + lr) * 32 + lko]);
        #pragma unroll
        for (int n = 0; n < 4; ++n)
            bf[n] = *reinterpret_cast<const f16x8*>(&sB[(wc + n * 16 + lr) * 32 + lko]);
        #pragma unroll
        for (int m = 0; m < 4; ++m)
            #pragma unroll
            for (int n = 0; n < 4; ++n)
                acc[m][n] = __builtin_amdgcn_mfma_f32_16x16x32_f16(af[m], bf[n], acc[m][n], 0, 0, 0);
        __syncthreads();
    }

    // C/D layout (m89-verified, dtype-independent): col = lane&15, row = (lane>>4)*4 + reg
    const int crow = bm * 128 + wr + ((l >> 4) << 2);
    const int ccol = bn * 128 + wc + lr;
    #pragma unroll
    for (int m = 0; m < 4; ++m)
        #pragma unroll
        for (int n = 0; n < 4; ++n)
            #pragma unroll
            for (int j = 0; j < 4; ++j)
                C[(size_t)(crow + m * 16 + j) * N_OUT + ccol + n * 16] = acc[m][n][j];
}

// ---------------- launcher ----------------

extern "C" void kernel_launch(void* const* d_in, const int* in_sizes, int n_in,
                              void* d_out, int out_size, void* d_ws, size_t ws_size,
                              hipStream_t stream) {
    const float* x   = (const float*)d_in[0];
    const float* wgt = (const float*)d_in[1];
    float* out = (float*)d_out;

    // workspace layout: [0,8K) double partials | [8K,16K) mean | Xh fp16 64MB | Wh fp16 32MB
    double*   partials = (double*)d_ws;
    float*    meanp    = (float*)((char*)d_ws + 8192);
    _Float16* Xh       = (_Float16*)((char*)d_ws + 16384);
    _Float16* Wh       = Xh + (size_t)M_TOK * K_IN;

    k_absmean_partial<<<1024, 256, 0, stream>>>(wgt, partials);
    k_absmean_final<<<1, 256, 0, stream>>>(partials, meanp);
    k_ternarize<<<2048, 256, 0, stream>>>(wgt, meanp, Wh);
    k_cvt_x<<<2048, 256, 0, stream>>>(x, Xh);

    dim3 grid(N_OUT / 128, M_TOK / 128);
    k_gemm<<<grid, 256, 0, stream>>>(Xh, Wh, out);
}

// Round 2
// 486.858 us; speedup vs baseline: 1.3759x; 1.3759x over previous
//
#include <hip/hip_runtime.h>

#define M_TOK 8192
#define N_OUT 4096
#define K_IN  4096
#define NT    (K_IN / 64)   // 64 K-tiles of BK=64

typedef _Float16 f16x8 __attribute__((ext_vector_type(8)));
typedef _Float16 f16x4 __attribute__((ext_vector_type(4)));
typedef float    f32x4 __attribute__((ext_vector_type(4)));

// ---------------- mean(|W|) reduction ----------------

__global__ void k_absmean_partial(const float* __restrict__ w, double* __restrict__ partials) {
    const int n4 = (N_OUT * K_IN) / 4;
    double s = 0.0;
    for (int i = blockIdx.x * blockDim.x + threadIdx.x; i < n4; i += gridDim.x * blockDim.x) {
        float4 v = reinterpret_cast<const float4*>(w)[i];
        s += (double)fabsf(v.x);
        s += (double)fabsf(v.y);
        s += (double)fabsf(v.z);
        s += (double)fabsf(v.w);
    }
    #pragma unroll
    for (int off = 32; off > 0; off >>= 1) s += __shfl_down(s, off, 64);
    __shared__ double sm[4];
    if ((threadIdx.x & 63) == 0) sm[threadIdx.x >> 6] = s;
    __syncthreads();
    if (threadIdx.x == 0) partials[blockIdx.x] = sm[0] + sm[1] + sm[2] + sm[3];
}

__global__ void k_absmean_final(const double* __restrict__ partials, float* __restrict__ meanp) {
    double s = 0.0;
    for (int i = threadIdx.x; i < 1024; i += 256) s += partials[i];
    #pragma unroll
    for (int off = 32; off > 0; off >>= 1) s += __shfl_down(s, off, 64);
    __shared__ double sm[4];
    if ((threadIdx.x & 63) == 0) sm[threadIdx.x >> 6] = s;
    __syncthreads();
    if (threadIdx.x == 0)
        *meanp = (float)((sm[0] + sm[1] + sm[2] + sm[3]) / (double)((long long)N_OUT * K_IN));
}

// ---------------- ternarize W -> fp16, cast x -> fp16 ----------------

__global__ void k_ternarize(const float* __restrict__ w, const float* __restrict__ meanp,
                            _Float16* __restrict__ wt) {
    const float t = *meanp;
    const int n4 = (N_OUT * K_IN) / 4;
    for (int i = blockIdx.x * blockDim.x + threadIdx.x; i < n4; i += gridDim.x * blockDim.x) {
        float4 v = reinterpret_cast<const float4*>(w)[i];
        f16x4 r;
        r[0] = (_Float16)((fabsf(v.x) > t) ? ((v.x > 0.f) ? 1.f : -1.f) : 0.f);
        r[1] = (_Float16)((fabsf(v.y) > t) ? ((v.y > 0.f) ? 1.f : -1.f) : 0.f);
        r[2] = (_Float16)((fabsf(v.z) > t) ? ((v.z > 0.f) ? 1.f : -1.f) : 0.f);
        r[3] = (_Float16)((fabsf(v.w) > t) ? ((v.w > 0.f) ? 1.f : -1.f) : 0.f);
        reinterpret_cast<f16x4*>(wt)[i] = r;
    }
}

__global__ void k_cvt_x(const float* __restrict__ x, _Float16* __restrict__ xh) {
    const int n4 = (M_TOK * K_IN) / 4;
    for (int i = blockIdx.x * blockDim.x + threadIdx.x; i < n4; i += gridDim.x * blockDim.x) {
        float4 v = reinterpret_cast<const float4*>(x)[i];
        f16x4 r;
        r[0] = (_Float16)v.x;
        r[1] = (_Float16)v.y;
        r[2] = (_Float16)v.z;
        r[3] = (_Float16)v.w;
        reinterpret_cast<f16x4*>(xh)[i] = r;
    }
}

// ---------------- fp16 MFMA GEMM, 256x256 tile, 8-phase schedule ----------------
// C[m][n] = sum_k A[m][k]*B[n][k].  8 waves (2M x 4N), BK=64, LDS 128KB:
//   buf[2] x { Ah0 | Ah1 | Bh0 | Bh1 }, each half-region 128 rows x 64 halfs (16KB).
// Quadrant phases per K-tile: (0,0) (0,1) (1,1) (1,0); per phase 16 MFMA/wave.
// Staging 1 half/phase into regions freed >=1 barrier earlier:
//   P1: B0_{t+1}->nxt  P2: A1_{t+1}->nxt  P3: A0_{t+2}->cur  P4: B1_{t+2}->cur
// Boundary wait vmcnt(4): completes exactly K-tile t+1's 4 halves (8 loads),
// leaves 2 halves of t+2 in flight across barriers (T4 counted vmcnt).
// T2 swizzle: LDS(row, c16) holds global c16 ^ (row&7); read XOR folds to lane&7.

__device__ __forceinline__ void g2lds16(const _Float16* g, _Float16* l) {
    __builtin_amdgcn_global_load_lds(
        (const __attribute__((address_space(1))) unsigned int*)g,
        (__attribute__((address_space(3))) unsigned int*)l, 16, 0, 0);
}

__global__ __launch_bounds__(512, 2) void k_gemm(const _Float16* __restrict__ A,
                                                 const _Float16* __restrict__ B,
                                                 float* __restrict__ C) {
    __shared__ _Float16 lds[65536];   // 128 KiB
    const int tid  = threadIdx.x;
    const int lane = tid & 63;
    const int wid  = tid >> 6;
    const int wm   = wid >> 2;        // 0..1
    const int wn   = wid & 3;         // 0..3
    const int lr   = lane & 15;
    const int lg   = lane >> 4;       // 0..3
    const int xv   = lr & 7;          // read-side swizzle XOR (rows ≡ lr mod 8)
    const int bm   = blockIdx.y, bn = blockIdx.x;

    const _Float16* gA = A + (size_t)bm * 256 * K_IN;
    const _Float16* gB = B + (size_t)bn * 256 * K_IN;

    // staging: thread i -> linear LDS (row = load*64 + i>>3, c16 = i&7);
    // global source col pre-swizzled so LDS(row,c16) holds global c16^(row&7)
    const int srow = tid >> 3;                        // 0..63
    const int scol = ((tid & 7) ^ (srow & 7)) << 3;   // halfs
    const int swb  = wid * 512;                       // wave-uniform base within load region

#define STAGE(gb, matOff, half, kt, buf) do {                                         \
    g2lds16((gb) + (size_t)((half) * 128 + srow) * K_IN + (kt) * 64 + scol,           \
            &lds[(buf) * 32768 + (matOff) + (half) * 8192 + swb]);                    \
    g2lds16((gb) + (size_t)((half) * 128 + 64 + srow) * K_IN + (kt) * 64 + scol,      \
            &lds[(buf) * 32768 + (matOff) + (half) * 8192 + 4096 + swb]);             \
} while (0)

    f32x4 acc[4][4][2];   // [quadrant][mf][nf]
    const f32x4 vz = {0.f, 0.f, 0.f, 0.f};
    #pragma unroll
    for (int q = 0; q < 4; ++q)
        #pragma unroll
        for (int mf = 0; mf < 4; ++mf)
            #pragma unroll
            for (int nf = 0; nf < 2; ++nf) acc[q][mf][nf] = vz;

    // prologue: all of K-tile 0 (first 4 halves issued), then A0/B1 of K-tile 1
    STAGE(gA, 0,     0, 0, 0);   // A0_0
    STAGE(gB, 16384, 1, 0, 0);   // B1_0
    STAGE(gB, 16384, 0, 0, 0);   // B0_0
    STAGE(gA, 0,     1, 0, 0);   // A1_0
    STAGE(gA, 0,     0, 1, 1);   // A0_1
    STAGE(gB, 16384, 1, 1, 1);   // B1_1
    asm volatile("s_waitcnt vmcnt(4)" ::: "memory");   // K-tile 0 fully landed
    __builtin_amdgcn_s_barrier();

    const int arow = wm * 64 + lr;
    const int brow = wn * 32 + lr;

#define LDA(qm, cb) do {                                                              \
    _Pragma("unroll") for (int mf = 0; mf < 4; ++mf)                                  \
    _Pragma("unroll") for (int kk = 0; kk < 2; ++kk)                                  \
        af[mf][kk] = *reinterpret_cast<const f16x8*>(                                 \
            &lds[(cb) + (qm) * 8192 + (arow + mf * 16) * 64 + ((kk * 4 + lg) ^ xv) * 8]); \
} while (0)
#define LDB(qn, cb) do {                                                              \
    _Pragma("unroll") for (int nf = 0; nf < 2; ++nf)                                  \
    _Pragma("unroll") for (int kk = 0; kk < 2; ++kk)                                  \
        bf[nf][kk] = *reinterpret_cast<const f16x8*>(                                 \
            &lds[(cb) + 16384 + (qn) * 8192 + (brow + nf * 16) * 64 + ((kk * 4 + lg) ^ xv) * 8]); \
} while (0)
#define MFMAQ(q) do {                                                                 \
    __builtin_amdgcn_s_setprio(1);                                                    \
    _Pragma("unroll") for (int mf = 0; mf < 4; ++mf)                                  \
    _Pragma("unroll") for (int nf = 0; nf < 2; ++nf)                                  \
    _Pragma("unroll") for (int kk = 0; kk < 2; ++kk)                                  \
        acc[q][mf][nf] = __builtin_amdgcn_mfma_f32_16x16x32_f16(                      \
            af[mf][kk], bf[nf][kk], acc[q][mf][nf], 0, 0, 0);                         \
    __builtin_amdgcn_s_setprio(0);                                                    \
} while (0)

    for (int t = 0; t < NT; ++t) {
        const int cur = t & 1;
        const int cb  = cur * 32768;
        const int nxt = cur ^ 1;
        f16x8 af[4][2], bf[2][2];

        // ---- P1: quadrant (0,0) — reads Ah0,Bh0 ----
        LDA(0, cb); LDB(0, cb);
        if (t + 1 < NT) STAGE(gB, 16384, 0, t + 1, nxt);   // B0_{t+1}
        __builtin_amdgcn_s_barrier();
        asm volatile("s_waitcnt lgkmcnt(0)");
        MFMAQ(0);
        __builtin_amdgcn_s_barrier();

        // ---- P2: quadrant (0,1) — reads Bh1, reuse af ----
        LDB(1, cb);
        if (t + 1 < NT) STAGE(gA, 0, 1, t + 1, nxt);       // A1_{t+1}
        __builtin_amdgcn_s_barrier();
        asm volatile("s_waitcnt lgkmcnt(0)");
        MFMAQ(1);
        __builtin_amdgcn_s_barrier();

        // ---- P3: quadrant (1,1) — reads Ah1, reuse bf ----
        LDA(1, cb);
        if (t + 2 < NT) STAGE(gA, 0, 0, t + 2, cur);       // A0_{t+2} (Ah0 freed after P1)
        __builtin_amdgcn_s_barrier();
        asm volatile("s_waitcnt lgkmcnt(0)");
        MFMAQ(2);
        __builtin_amdgcn_s_barrier();

        // ---- P4: quadrant (1,0) — reads Bh0 again, reuse af ----
        LDB(0, cb);
        if (t + 2 < NT) STAGE(gB, 16384, 1, t + 2, cur);   // B1_{t+2} (Bh1 freed after P2)
        __builtin_amdgcn_s_barrier();
        asm volatile("s_waitcnt lgkmcnt(0)");
        MFMAQ(3);
        if (t < NT - 2) asm volatile("s_waitcnt vmcnt(4)" ::: "memory");  // t+1 halves landed
        else            asm volatile("s_waitcnt vmcnt(0)" ::: "memory");  // tail drain
        __builtin_amdgcn_s_barrier();
    }

    // epilogue: C/D layout col=lane&15, row=(lane>>4)*4+reg (m89-verified)
    const int qmv[4] = {0, 0, 1, 1}, qnv[4] = {0, 1, 1, 0};
    #pragma unroll
    for (int q = 0; q < 4; ++q)
        #pragma unroll
        for (int mf = 0; mf < 4; ++mf)
            #pragma unroll
            for (int nf = 0; nf < 2; ++nf)
                #pragma unroll
                for (int j = 0; j < 4; ++j) {
                    const int row = bm * 256 + qmv[q] * 128 + wm * 64 + mf * 16 + lg * 4 + j;
                    const int col = bn * 256 + qnv[q] * 128 + wn * 32 + nf * 16 + lr;
                    C[(size_t)row * N_OUT + col] = acc[q][mf][nf][j];
                }
#undef STAGE
#undef LDA
#undef LDB
#undef MFMAQ
}

// ---------------- launcher ----------------

extern "C" void kernel_launch(void* const* d_in, const int* in_sizes, int n_in,
                              void* d_out, int out_size, void* d_ws, size_t ws_size,
                              hipStream_t stream) {
    const float* x   = (const float*)d_in[0];
    const float* wgt = (const float*)d_in[1];
    float* out = (float*)d_out;

    // workspace: [0,8K) double partials | [8K,16K) mean | Xh fp16 64MB | Wh fp16 32MB
    double*   partials = (double*)d_ws;
    float*    meanp    = (float*)((char*)d_ws + 8192);
    _Float16* Xh       = (_Float16*)((char*)d_ws + 16384);
    _Float16* Wh       = Xh + (size_t)M_TOK * K_IN;

    k_absmean_partial<<<1024, 256, 0, stream>>>(wgt, partials);
    k_absmean_final<<<1, 256, 0, stream>>>(partials, meanp);
    k_ternarize<<<2048, 256, 0, stream>>>(wgt, meanp, Wh);
    k_cvt_x<<<2048, 256, 0, stream>>>(x, Xh);

    dim3 grid(N_OUT / 256, M_TOK / 256);   // (16, 32)
    k_gemm<<<grid, 512, 0, stream>>>(Xh, Wh, out);
}

// Round 4
// 478.637 us; speedup vs baseline: 1.3995x; 1.0172x over previous
//
#include <hip/hip_runtime.h>

#define M_TOK 8192
#define N_OUT 4096
#define K_IN  4096
#define NT    (K_IN / 64)   // 64 K-tiles of BK=64

typedef _Float16 f16x8 __attribute__((ext_vector_type(8)));
typedef _Float16 f16x4 __attribute__((ext_vector_type(4)));
typedef float    f32x4 __attribute__((ext_vector_type(4)));

// ---------------- mean(|W|) reduction ----------------

__global__ void k_absmean_partial(const float* __restrict__ w, double* __restrict__ partials) {
    const int n4 = (N_OUT * K_IN) / 4;
    double s = 0.0;
    for (int i = blockIdx.x * blockDim.x + threadIdx.x; i < n4; i += gridDim.x * blockDim.x) {
        float4 v = reinterpret_cast<const float4*>(w)[i];
        s += (double)fabsf(v.x);
        s += (double)fabsf(v.y);
        s += (double)fabsf(v.z);
        s += (double)fabsf(v.w);
    }
    #pragma unroll
    for (int off = 32; off > 0; off >>= 1) s += __shfl_down(s, off, 64);
    __shared__ double sm[4];
    if ((threadIdx.x & 63) == 0) sm[threadIdx.x >> 6] = s;
    __syncthreads();
    if (threadIdx.x == 0) partials[blockIdx.x] = sm[0] + sm[1] + sm[2] + sm[3];
}

__global__ void k_absmean_final(const double* __restrict__ partials, float* __restrict__ meanp) {
    double s = 0.0;
    for (int i = threadIdx.x; i < 1024; i += 256) s += partials[i];
    #pragma unroll
    for (int off = 32; off > 0; off >>= 1) s += __shfl_down(s, off, 64);
    __shared__ double sm[4];
    if ((threadIdx.x & 63) == 0) sm[threadIdx.x >> 6] = s;
    __syncthreads();
    if (threadIdx.x == 0)
        *meanp = (float)((sm[0] + sm[1] + sm[2] + sm[3]) / (double)((long long)N_OUT * K_IN));
}

// ---------------- fused: ternarize W -> fp16 AND cast x -> fp16 ----------------

__global__ void k_prep(const float* __restrict__ w, const float* __restrict__ x,
                       const float* __restrict__ meanp,
                       _Float16* __restrict__ wh, _Float16* __restrict__ xh) {
    const float t = *meanp;
    const int stride = gridDim.x * blockDim.x;
    const int nw4 = (N_OUT * K_IN) / 4;
    for (int i = blockIdx.x * blockDim.x + threadIdx.x; i < nw4; i += stride) {
        float4 v = reinterpret_cast<const float4*>(w)[i];
        f16x4 r;
        r[0] = (_Float16)((fabsf(v.x) > t) ? ((v.x > 0.f) ? 1.f : -1.f) : 0.f);
        r[1] = (_Float16)((fabsf(v.y) > t) ? ((v.y > 0.f) ? 1.f : -1.f) : 0.f);
        r[2] = (_Float16)((fabsf(v.z) > t) ? ((v.z > 0.f) ? 1.f : -1.f) : 0.f);
        r[3] = (_Float16)((fabsf(v.w) > t) ? ((v.w > 0.f) ? 1.f : -1.f) : 0.f);
        reinterpret_cast<f16x4*>(wh)[i] = r;
    }
    const int nx4 = (M_TOK * K_IN) / 4;
    for (int i = blockIdx.x * blockDim.x + threadIdx.x; i < nx4; i += stride) {
        float4 v = reinterpret_cast<const float4*>(x)[i];
        f16x4 r;
        r[0] = (_Float16)v.x;
        r[1] = (_Float16)v.y;
        r[2] = (_Float16)v.z;
        r[3] = (_Float16)v.w;
        reinterpret_cast<f16x4*>(xh)[i] = r;
    }
}

// ---------------- fp16 MFMA GEMM, 256x256 tile, pipelined 4-phase schedule ----------------
// C[m][n] = sum_k A[m][k]*B[n][k].  8 waves (2M x 4N), BK=64, LDS 128KB:
//   buf[2] x { Ah0 | Ah1 | Bh0 | Bh1 }, each 128 rows x 64 halfs (16KB).
// Quadrants Q0=(0,0) Q1=(0,1) Q2=(1,1) Q3=(1,0); 16 MFMA each.
// Fragment reads are issued one phase AHEAD of their MFMA cluster so the LDS
// drain overlaps MFMA (no lgkmcnt(0) asm — compiler inserts counted waits):
//   P1: stage B0_{t+1}->nxt | read bf0,bf1(cur) | MFMA Q0(af0,bf0)
//   P2: stage A1_{t+1}->nxt | read af1(cur)     | MFMA Q1(af0,bf1)  | BARRIER
//   P3: stage A0_{t+2}->cur |                     MFMA Q2(af1,bf1)
//   P4: stage B1_{t+2}->cur | vmcnt(4) | BARRIER | read af0(nxt) | MFMA Q3(af1,bf0)
// Race proof sketch: every LDS region's (read-complete -> overwrite-issue)
// interval crosses >=1 barrier; hoisted af0(nxt) reads sit AFTER the barrier
// that follows every wave's vmcnt(4) (vmcnt is per-wave; cross-wave slice
// visibility requires barrier-after-vmcnt). bf0 held in regs for Q3.
// T2 swizzle: LDS(row,c16) holds global c16 ^ (row&7); read XOR folds to lane&7.

__device__ __forceinline__ void g2lds16(const _Float16* g, _Float16* l) {
    __builtin_amdgcn_global_load_lds(
        (const __attribute__((address_space(1))) unsigned int*)g,
        (__attribute__((address_space(3))) unsigned int*)l, 16, 0, 0);
}

#define BAR() do { asm volatile("" ::: "memory"); \
                   __builtin_amdgcn_s_barrier();  \
                   asm volatile("" ::: "memory"); } while (0)

__global__ __launch_bounds__(512, 2) void k_gemm(const _Float16* __restrict__ A,
                                                 const _Float16* __restrict__ B,
                                                 float* __restrict__ C) {
    __shared__ _Float16 lds[65536];   // 128 KiB
    const int tid  = threadIdx.x;
    const int lane = tid & 63;
    const int wid  = tid >> 6;
    const int wm   = wid >> 2;        // 0..1
    const int wn   = wid & 3;         // 0..3
    const int lr   = lane & 15;
    const int lg   = lane >> 4;       // 0..3
    const int xv   = lr & 7;          // read-side swizzle XOR
    const int bm   = blockIdx.y, bn = blockIdx.x;

    const _Float16* gA = A + (size_t)bm * 256 * K_IN;
    const _Float16* gB = B + (size_t)bn * 256 * K_IN;

    // staging: thread i -> linear LDS (row = i>>3, c16 = i&7);
    // global source col pre-swizzled so LDS(row,c16) holds global c16^(row&7)
    const int srow = tid >> 3;                        // 0..63
    const int scol = ((tid & 7) ^ (srow & 7)) << 3;   // halfs
    const int swb  = wid * 512;                       // wave-uniform base

#define STAGE(gb, matOff, half, kt, buf) do {                                         \
    g2lds16((gb) + (size_t)((half) * 128 + srow) * K_IN + (kt) * 64 + scol,           \
            &lds[(buf) * 32768 + (matOff) + (half) * 8192 + swb]);                    \
    g2lds16((gb) + (size_t)((half) * 128 + 64 + srow) * K_IN + (kt) * 64 + scol,      \
            &lds[(buf) * 32768 + (matOff) + (half) * 8192 + 4096 + swb]);             \
} while (0)

    const int arow = wm * 64 + lr;
    const int brow = wn * 32 + lr;
    const int ka0  = (lg ^ xv) * 8;         // kk=0 swizzled offset (halfs)
    const int ka1  = ((4 + lg) ^ xv) * 8;   // kk=1

#define RD_A(dst, qm, cb0) do {                                                       \
    _Pragma("unroll") for (int mf = 0; mf < 4; ++mf) {                                \
        const _Float16* p_ = &lds[(cb0) + (qm) * 8192 + (arow + mf * 16) * 64];       \
        dst[mf][0] = *reinterpret_cast<const f16x8*>(p_ + ka0);                       \
        dst[mf][1] = *reinterpret_cast<const f16x8*>(p_ + ka1);                       \
    }                                                                                 \
} while (0)
#define RD_B(dst, qn, cb0) do {                                                       \
    _Pragma("unroll") for (int nf = 0; nf < 2; ++nf) {                                \
        const _Float16* p_ = &lds[(cb0) + 16384 + (qn) * 8192 + (brow + nf * 16) * 64]; \
        dst[nf][0] = *reinterpret_cast<const f16x8*>(p_ + ka0);                       \
        dst[nf][1] = *reinterpret_cast<const f16x8*>(p_ + ka1);                       \
    }                                                                                 \
} while (0)
#define MFMAQ(q, afx, bfx) do {                                                       \
    __builtin_amdgcn_s_setprio(1);                                                    \
    _Pragma("unroll") for (int mf = 0; mf < 4; ++mf)                                  \
    _Pragma("unroll") for (int nf = 0; nf < 2; ++nf)                                  \
    _Pragma("unroll") for (int kk = 0; kk < 2; ++kk)                                  \
        acc[q][mf][nf] = __builtin_amdgcn_mfma_f32_16x16x32_f16(                      \
            afx[mf][kk], bfx[nf][kk], acc[q][mf][nf], 0, 0, 0);                       \
    __builtin_amdgcn_s_setprio(0);                                                    \
} while (0)

    f32x4 acc[4][4][2];
    const f32x4 vz = {0.f, 0.f, 0.f, 0.f};
    #pragma unroll
    for (int q = 0; q < 4; ++q)
        #pragma unroll
        for (int mf = 0; mf < 4; ++mf)
            #pragma unroll
            for (int nf = 0; nf < 2; ++nf) acc[q][mf][nf] = vz;

    f16x8 af0[4][2], af1[4][2], bf0[2][2], bf1[2][2];

    // prologue: K-tile 0 fully staged + A0/B1 of K-tile 1; then hoist af0 reads
    STAGE(gA, 0,     0, 0, 0);   // A0_0
    STAGE(gB, 16384, 1, 0, 0);   // B1_0
    STAGE(gB, 16384, 0, 0, 0);   // B0_0
    STAGE(gA, 0,     1, 0, 0);   // A1_0
    STAGE(gA, 0,     0, 1, 1);   // A0_1
    STAGE(gB, 16384, 1, 1, 1);   // B1_1
    asm volatile("s_waitcnt vmcnt(4)" ::: "memory");   // K-tile 0 landed
    BAR();
    RD_A(af0, 0, 0);

    for (int t = 0; t < NT; ++t) {
        const int cur = t & 1;
        const int cb  = cur * 32768;
        const int nxt = cur ^ 1;
        const int nb  = nxt * 32768;

        // ---- P1: Q0 = (0,0) ----
        if (t + 1 < NT) STAGE(gB, 16384, 0, t + 1, nxt);   // B0_{t+1}
        RD_B(bf0, 0, cb);
        RD_B(bf1, 1, cb);
        MFMAQ(0, af0, bf0);

        // ---- P2: Q1 = (0,1) ----
        if (t + 1 < NT) STAGE(gA, 0, 1, t + 1, nxt);       // A1_{t+1}
        RD_A(af1, 1, cb);
        MFMAQ(1, af0, bf1);
        BAR();

        // ---- P3: Q2 = (1,1) ----
        if (t + 2 < NT) STAGE(gA, 0, 0, t + 2, cur);       // A0_{t+2}
        MFMAQ(2, af1, bf1);

        // ---- P4: Q3 = (1,0) ----
        if (t + 2 < NT) STAGE(gB, 16384, 1, t + 2, cur);   // B1_{t+2}
        if (t < NT - 2) asm volatile("s_waitcnt vmcnt(4)" ::: "memory");
        else            asm volatile("s_waitcnt vmcnt(0)" ::: "memory");
        BAR();
        if (t + 1 < NT) RD_A(af0, 0, nb);                  // hoisted Q0 reads for t+1
        MFMAQ(3, af1, bf0);
    }

    // epilogue: C/D layout col=lane&15, row=(lane>>4)*4+reg (m89-verified)
    const int qmv[4] = {0, 0, 1, 1}, qnv[4] = {0, 1, 1, 0};
    #pragma unroll
    for (int q = 0; q < 4; ++q)
        #pragma unroll
        for (int mf = 0; mf < 4; ++mf)
            #pragma unroll
            for (int nf = 0; nf < 2; ++nf)
                #pragma unroll
                for (int j = 0; j < 4; ++j) {
                    const int row = bm * 256 + qmv[q] * 128 + wm * 64 + mf * 16 + lg * 4 + j;
                    const int col = bn * 256 + qnv[q] * 128 + wn * 32 + nf * 16 + lr;
                    C[(size_t)row * N_OUT + col] = acc[q][mf][nf][j];
                }
#undef STAGE
#undef RD_A
#undef RD_B
#undef MFMAQ
}

// ---------------- launcher ----------------

extern "C" void kernel_launch(void* const* d_in, const int* in_sizes, int n_in,
                              void* d_out, int out_size, void* d_ws, size_t ws_size,
                              hipStream_t stream) {
    const float* x   = (const float*)d_in[0];
    const float* wgt = (const float*)d_in[1];
    float* out = (float*)d_out;

    // workspace: [0,8K) double partials | [8K,16K) mean | Xh fp16 64MB | Wh fp16 32MB
    double*   partials = (double*)d_ws;
    float*    meanp    = (float*)((char*)d_ws + 8192);
    _Float16* Xh       = (_Float16*)((char*)d_ws + 16384);
    _Float16* Wh       = Xh + (size_t)M_TOK * K_IN;

    k_absmean_partial<<<1024, 256, 0, stream>>>(wgt, partials);
    k_absmean_final<<<1, 256, 0, stream>>>(partials, meanp);
    k_prep<<<2048, 256, 0, stream>>>(wgt, x, meanp, Wh, Xh);

    dim3 grid(N_OUT / 256, M_TOK / 256);   // (16, 32)
    k_gemm<<<grid, 512, 0, stream>>>(Xh, Wh, out);
}

// Round 5
// 470.790 us; speedup vs baseline: 1.4229x; 1.0167x over previous
//
#include <hip/hip_runtime.h>

#define M_TOK 8192
#define N_OUT 4096
#define K_IN  4096
#define NT    (K_IN / 64)   // 64 K-tiles of BK=64

typedef _Float16 f16x8 __attribute__((ext_vector_type(8)));
typedef _Float16 f16x4 __attribute__((ext_vector_type(4)));
typedef float    f32x4 __attribute__((ext_vector_type(4)));

// ---------------- mean(|W|) reduction ----------------

__global__ void k_absmean_partial(const float* __restrict__ w, double* __restrict__ partials) {
    const int n4 = (N_OUT * K_IN) / 4;
    double s = 0.0;
    for (int i = blockIdx.x * blockDim.x + threadIdx.x; i < n4; i += gridDim.x * blockDim.x) {
        float4 v = reinterpret_cast<const float4*>(w)[i];
        s += (double)fabsf(v.x);
        s += (double)fabsf(v.y);
        s += (double)fabsf(v.z);
        s += (double)fabsf(v.w);
    }
    #pragma unroll
    for (int off = 32; off > 0; off >>= 1) s += __shfl_down(s, off, 64);
    __shared__ double sm[4];
    if ((threadIdx.x & 63) == 0) sm[threadIdx.x >> 6] = s;
    __syncthreads();
    if (threadIdx.x == 0) partials[blockIdx.x] = sm[0] + sm[1] + sm[2] + sm[3];
}

__global__ void k_absmean_final(const double* __restrict__ partials, float* __restrict__ meanp) {
    double s = 0.0;
    for (int i = threadIdx.x; i < 1024; i += 256) s += partials[i];
    #pragma unroll
    for (int off = 32; off > 0; off >>= 1) s += __shfl_down(s, off, 64);
    __shared__ double sm[4];
    if ((threadIdx.x & 63) == 0) sm[threadIdx.x >> 6] = s;
    __syncthreads();
    if (threadIdx.x == 0)
        *meanp = (float)((sm[0] + sm[1] + sm[2] + sm[3]) / (double)((long long)N_OUT * K_IN));
}

// ---------------- fused: ternarize W -> fp16 AND cast x -> fp16 ----------------

__global__ void k_prep(const float* __restrict__ w, const float* __restrict__ x,
                       const float* __restrict__ meanp,
                       _Float16* __restrict__ wh, _Float16* __restrict__ xh) {
    const float t = *meanp;
    const int stride = gridDim.x * blockDim.x;
    const int nw4 = (N_OUT * K_IN) / 4;
    for (int i = blockIdx.x * blockDim.x + threadIdx.x; i < nw4; i += stride) {
        float4 v = reinterpret_cast<const float4*>(w)[i];
        f16x4 r;
        r[0] = (_Float16)((fabsf(v.x) > t) ? ((v.x > 0.f) ? 1.f : -1.f) : 0.f);
        r[1] = (_Float16)((fabsf(v.y) > t) ? ((v.y > 0.f) ? 1.f : -1.f) : 0.f);
        r[2] = (_Float16)((fabsf(v.z) > t) ? ((v.z > 0.f) ? 1.f : -1.f) : 0.f);
        r[3] = (_Float16)((fabsf(v.w) > t) ? ((v.w > 0.f) ? 1.f : -1.f) : 0.f);
        reinterpret_cast<f16x4*>(wh)[i] = r;
    }
    const int nx4 = (M_TOK * K_IN) / 4;
    for (int i = blockIdx.x * blockDim.x + threadIdx.x; i < nx4; i += stride) {
        float4 v = reinterpret_cast<const float4*>(x)[i];
        f16x4 r;
        r[0] = (_Float16)v.x;
        r[1] = (_Float16)v.y;
        r[2] = (_Float16)v.z;
        r[3] = (_Float16)v.w;
        reinterpret_cast<f16x4*>(xh)[i] = r;
    }
}

// ---------------- fp16 MFMA GEMM, 256x256 tile, fully read-covered schedule --------------
// C[m][n] = sum_k A[m][k]*B[n][k].  8 waves (2M x 4N), BK=64, LDS 128KB:
//   buf[2] x { Ah0 | Ah1 | Bh0 | Bh1 }, each 128 rows x 64 halfs (16KB).
// Cluster order C1=(0,0) C2=(1,0) C3=(0,1) C4=(1,1): last cluster shares NO frag with
// first, so the boundary reloads (af0n, bf0n) overwrite dead registers.
// Every ds_read group drains under the PREVIOUS MFMA cluster (reads one cluster ahead):
//   P1: stage B0_{t+1}->nxt | read af1 (for C2)  | MFMA C1(af0,bf0)
//   P2: stage A1_{t+1}->nxt | read bf1 (for C3)  | MFMA C2(af1,bf0) | BARRIER
//   P3: stage A0_{t+2}->cur |                      MFMA C3(af0,bf1)
//   P4: stage B1_{t+2}->cur | vmcnt(4) | BARRIER | read af0n,bf0n  | MFMA C4(af1,bf1)
// vmcnt(4): 12 outstanding at that point; completes the 8 oldest = all of K-tile t+1,
// leaves A0_{t+2},B1_{t+2} in flight across the barrier (T4 counted vmcnt).
// Region safety: every LDS region's (read-complete -> overwrite-issue) interval crosses
// >=1 barrier; nxt-buffer reads sit AFTER the barrier following every wave's vmcnt(4).
// T2 swizzle: LDS(row,c16) holds global c16 ^ (row&7); read XOR folds to lane&7.

__device__ __forceinline__ void g2lds16(const _Float16* g, _Float16* l) {
    __builtin_amdgcn_global_load_lds(
        (const __attribute__((address_space(1))) unsigned int*)g,
        (__attribute__((address_space(3))) unsigned int*)l, 16, 0, 0);
}

#define BAR() do { asm volatile("" ::: "memory"); \
                   __builtin_amdgcn_s_barrier();  \
                   asm volatile("" ::: "memory"); } while (0)

__global__ __launch_bounds__(512, 2) void k_gemm(const _Float16* __restrict__ A,
                                                 const _Float16* __restrict__ B,
                                                 float* __restrict__ C) {
    __shared__ _Float16 lds[65536];   // 128 KiB
    const int tid  = threadIdx.x;
    const int lane = tid & 63;
    const int wid  = tid >> 6;
    const int wm   = wid >> 2;        // 0..1
    const int wn   = wid & 3;         // 0..3
    const int lr   = lane & 15;
    const int lg   = lane >> 4;       // 0..3
    const int xv   = lr & 7;          // read-side swizzle XOR
    const int bm   = blockIdx.y, bn = blockIdx.x;

    const _Float16* gA = A + (size_t)bm * 256 * K_IN;
    const _Float16* gB = B + (size_t)bn * 256 * K_IN;

    // staging: thread i -> linear LDS (row = i>>3, c16 = i&7);
    // global source col pre-swizzled so LDS(row,c16) holds global c16^(row&7)
    const int srow = tid >> 3;                        // 0..63
    const int scol = ((tid & 7) ^ (srow & 7)) << 3;   // halfs
    const int swb  = wid * 512;                       // wave-uniform base

#define STAGE(gb, matOff, half, kt, buf) do {                                         \
    g2lds16((gb) + (size_t)((half) * 128 + srow) * K_IN + (kt) * 64 + scol,           \
            &lds[(buf) * 32768 + (matOff) + (half) * 8192 + swb]);                    \
    g2lds16((gb) + (size_t)((half) * 128 + 64 + srow) * K_IN + (kt) * 64 + scol,      \
            &lds[(buf) * 32768 + (matOff) + (half) * 8192 + 4096 + swb]);             \
} while (0)

    const int arow = wm * 64 + lr;
    const int brow = wn * 32 + lr;
    const int ka0  = (lg ^ xv) * 8;         // kk=0 swizzled offset (halfs)
    const int ka1  = ((4 + lg) ^ xv) * 8;   // kk=1

#define RD_A(dst, qm, cb0) do {                                                       \
    _Pragma("unroll") for (int mf = 0; mf < 4; ++mf) {                                \
        const _Float16* p_ = &lds[(cb0) + (qm) * 8192 + (arow + mf * 16) * 64];       \
        dst[mf][0] = *reinterpret_cast<const f16x8*>(p_ + ka0);                       \
        dst[mf][1] = *reinterpret_cast<const f16x8*>(p_ + ka1);                       \
    }                                                                                 \
} while (0)
#define RD_B(dst, qn, cb0) do {                                                       \
    _Pragma("unroll") for (int nf = 0; nf < 2; ++nf) {                                \
        const _Float16* p_ = &lds[(cb0) + 16384 + (qn) * 8192 + (brow + nf * 16) * 64]; \
        dst[nf][0] = *reinterpret_cast<const f16x8*>(p_ + ka0);                       \
        dst[nf][1] = *reinterpret_cast<const f16x8*>(p_ + ka1);                       \
    }                                                                                 \
} while (0)
#define MFMAQ(q, afx, bfx) do {                                                       \
    __builtin_amdgcn_s_setprio(1);                                                    \
    _Pragma("unroll") for (int mf = 0; mf < 4; ++mf)                                  \
    _Pragma("unroll") for (int nf = 0; nf < 2; ++nf)                                  \
    _Pragma("unroll") for (int kk = 0; kk < 2; ++kk)                                  \
        acc[q][mf][nf] = __builtin_amdgcn_mfma_f32_16x16x32_f16(                      \
            afx[mf][kk], bfx[nf][kk], acc[q][mf][nf], 0, 0, 0);                       \
    __builtin_amdgcn_s_setprio(0);                                                    \
} while (0)

    f32x4 acc[4][4][2];
    const f32x4 vz = {0.f, 0.f, 0.f, 0.f};
    #pragma unroll
    for (int q = 0; q < 4; ++q)
        #pragma unroll
        for (int mf = 0; mf < 4; ++mf)
            #pragma unroll
            for (int nf = 0; nf < 2; ++nf) acc[q][mf][nf] = vz;

    f16x8 af0[4][2], af1[4][2], bf0[2][2], bf1[2][2];

    // prologue: K-tile 0 fully staged + A0/B1 of K-tile 1; hoist af0+bf0 reads
    STAGE(gA, 0,     0, 0, 0);   // A0_0
    STAGE(gB, 16384, 1, 0, 0);   // B1_0
    STAGE(gB, 16384, 0, 0, 0);   // B0_0
    STAGE(gA, 0,     1, 0, 0);   // A1_0
    STAGE(gA, 0,     0, 1, 1);   // A0_1
    STAGE(gB, 16384, 1, 1, 1);   // B1_1
    asm volatile("s_waitcnt vmcnt(4)" ::: "memory");   // K-tile 0 landed
    BAR();
    RD_A(af0, 0, 0);
    RD_B(bf0, 0, 0);

    for (int t = 0; t < NT; ++t) {
        const int cur = t & 1;
        const int cb  = cur * 32768;
        const int nxt = cur ^ 1;
        const int nb  = nxt * 32768;

        // ---- P1: C1 = (0,0) — af0,bf0 (read at prev boundary) ----
        if (t + 1 < NT) STAGE(gB, 16384, 0, t + 1, nxt);   // B0_{t+1}
        RD_A(af1, 1, cb);                                  // for C2, drains under C1
        MFMAQ(0, af0, bf0);

        // ---- P2: C2 = (1,0) — af1,bf0 ----
        if (t + 1 < NT) STAGE(gA, 0, 1, t + 1, nxt);       // A1_{t+1}
        RD_B(bf1, 1, cb);                                  // for C3, drains under C2
        MFMAQ(1, af1, bf0);
        BAR();

        // ---- P3: C3 = (0,1) — af0,bf1 ----
        if (t + 2 < NT) STAGE(gA, 0, 0, t + 2, cur);       // A0_{t+2} (region freed: read done pre-C1, barrier crossed)
        MFMAQ(2, af0, bf1);

        // ---- P4: C4 = (1,1) — af1,bf1 (no new frags) ----
        if (t + 2 < NT) STAGE(gB, 16384, 1, t + 2, cur);   // B1_{t+2}
        if (t < NT - 2) asm volatile("s_waitcnt vmcnt(4)" ::: "memory");
        else            asm volatile("s_waitcnt vmcnt(0)" ::: "memory");
        BAR();
        if (t + 1 < NT) {
            RD_A(af0, 0, nb);                              // boundary reads drain under C4
            RD_B(bf0, 0, nb);                              // (af0 dead after C3, bf0 dead after C2)
        }
        MFMAQ(3, af1, bf1);
    }

    // epilogue: C/D layout col=lane&15, row=(lane>>4)*4+reg (m89-verified)
    // cluster -> (qm, qn): 0->(0,0) 1->(1,0) 2->(0,1) 3->(1,1)
    const int qmv[4] = {0, 1, 0, 1}, qnv[4] = {0, 0, 1, 1};
    #pragma unroll
    for (int q = 0; q < 4; ++q)
        #pragma unroll
        for (int mf = 0; mf < 4; ++mf)
            #pragma unroll
            for (int nf = 0; nf < 2; ++nf)
                #pragma unroll
                for (int j = 0; j < 4; ++j) {
                    const int row = bm * 256 + qmv[q] * 128 + wm * 64 + mf * 16 + lg * 4 + j;
                    const int col = bn * 256 + qnv[q] * 128 + wn * 32 + nf * 16 + lr;
                    C[(size_t)row * N_OUT + col] = acc[q][mf][nf][j];
                }
#undef STAGE
#undef RD_A
#undef RD_B
#undef MFMAQ
}

// ---------------- launcher ----------------

extern "C" void kernel_launch(void* const* d_in, const int* in_sizes, int n_in,
                              void* d_out, int out_size, void* d_ws, size_t ws_size,
                              hipStream_t stream) {
    const float* x   = (const float*)d_in[0];
    const float* wgt = (const float*)d_in[1];
    float* out = (float*)d_out;

    // workspace: [0,8K) double partials | [8K,16K) mean | Xh fp16 64MB | Wh fp16 32MB
    double*   partials = (double*)d_ws;
    float*    meanp    = (float*)((char*)d_ws + 8192);
    _Float16* Xh       = (_Float16*)((char*)d_ws + 16384);
    _Float16* Wh       = Xh + (size_t)M_TOK * K_IN;

    k_absmean_partial<<<1024, 256, 0, stream>>>(wgt, partials);
    k_absmean_final<<<1, 256, 0, stream>>>(partials, meanp);
    k_prep<<<2048, 256, 0, stream>>>(wgt, x, meanp, Wh, Xh);

    dim3 grid(N_OUT / 256, M_TOK / 256);   // (16, 32)
    k_gemm<<<grid, 512, 0, stream>>>(Xh, Wh, out);
}